// Round 6
// baseline (203.600 us; speedup 1.0000x reference)
//
#include <hip/hip_runtime.h>

// ---------------------------------------------------------------------------
// DSTGCN fused pipeline, MI355X gfx950.
// k_prep : LN(node+time)->e,eq | x->xT (LDS-tiled) | ne_bf | wpT | bias
// k_attn : flash attention, no-max softmax (LN bounds |logit|<=64),
//          S^T = K.Q^T (P exits MFMA with lane=q), PV A-frags in-register.
//          K/V double-buffered via explicit named registers (macro form —
//          round-5's struct+lambda form failed validation; this is the
//          bisect of that change against the known-good round-4 base).
// k_hyper: EXACT round-4 version (known good).
// ---------------------------------------------------------------------------

using bf16x8 = __attribute__((ext_vector_type(8))) __bf16;
using f32x4  = __attribute__((ext_vector_type(4))) float;
using f32x16 = __attribute__((ext_vector_type(16))) float;

__device__ __forceinline__ unsigned short f2bf_bits(float f) {
    unsigned int u = __float_as_uint(f);
    u += 0x7fffu + ((u >> 16) & 1u);          // RNE
    return (unsigned short)(u >> 16);
}

__device__ __forceinline__ f32x4 mfma16(bf16x8 a, bf16x8 b, f32x4 c) {
    return __builtin_amdgcn_mfma_f32_16x16x32_bf16(a, b, c, 0, 0, 0);
}
__device__ __forceinline__ f32x16 mfma32(bf16x8 a, bf16x8 b, f32x16 c) {
    return __builtin_amdgcn_mfma_f32_32x32x16_bf16(a, b, c, 0, 0, 0);
}
__device__ __forceinline__ f32x16 zero16() {
    f32x16 z;
    #pragma unroll
    for (int i = 0; i < 16; ++i) z[i] = 0.f;
    return z;
}

// ---------------- k_prep: all preprocessing in one launch ------------------
__global__ __launch_bounds__(256) void k_prep(const float* __restrict__ x,
                                              const float* __restrict__ node_emb,
                                              const float* __restrict__ time_emb,
                                              const float* __restrict__ wp,
                                              const float* __restrict__ bias_pool,
                                              const float* __restrict__ gamma,
                                              const float* __restrict__ beta,
                                              unsigned short* __restrict__ e_bf,
                                              unsigned short* __restrict__ eq_bf,
                                              unsigned short* __restrict__ xT,
                                              unsigned short* __restrict__ ne_bf,
                                              unsigned short* __restrict__ wpT,
                                              float* __restrict__ biasw) {
    __shared__ float tile[64 * 65];
    const int b = blockIdx.x;
    const int t = threadIdx.x;
    if (b < 6144) {                               // ---- LayerNorm ----
        int row  = b * 4 + (t >> 6);              // bt*4096+n
        int lane = t & 63;
        int bt = row >> 12, n = row & 4095;
        float v = node_emb[(n << 6) | lane] + time_emb[(bt << 6) | lane];
        float s = v, s2 = v * v;
        #pragma unroll
        for (int off = 32; off; off >>= 1) {
            s  += __shfl_xor(s,  off);
            s2 += __shfl_xor(s2, off);
        }
        float mu  = s * 0.015625f;
        float var = s2 * 0.015625f - mu * mu;
        float r   = rsqrtf(var + 1e-12f);
        float o   = (v - mu) * r * gamma[lane] + beta[lane];
        e_bf [(row << 6) | lane] = f2bf_bits(o);
        eq_bf[(row << 6) | lane] = f2bf_bits(o * 1.44269504f);
    } else if (b < 6528) {                        // ---- x transpose ----
        int bb = b - 6144;
        int bt = bb >> 6, n0 = (bb & 63) << 6;
        const float* xr = x + ((size_t)((bt << 12) | n0) << 6);
        #pragma unroll
        for (int it = 0; it < 16; ++it) {
            int i = (it << 2) + (t >> 6);
            int d = t & 63;
            tile[i * 65 + d] = xr[(i << 6) + d];  // coalesced 256B rows
        }
        __syncthreads();
        unsigned short* dst = xT + ((size_t)bt << 18) + n0;
        #pragma unroll
        for (int it = 0; it < 16; ++it) {
            int d = (it << 2) + (t >> 6);
            int n = t & 63;
            dst[((size_t)d << 12) + n] = f2bf_bits(tile[n * 65 + d]);
        }
    } else if (b < 7552) {                        // ---- ne_bf ----
        int idx = (b - 6528) * 256 + t;
        ne_bf[idx] = f2bf_bits(node_emb[idx]);
    } else if (b < 7680) {                        // ---- wpT ----
        int ki = b - 7552;
        #pragma unroll
        for (int it = 0; it < 16; ++it) {
            int d = (it << 2) + (t >> 6);
            int o = t & 63;
            tile[d * 65 + o] = wp[(d << 13) + (ki << 6) + o];
        }
        __syncthreads();
        #pragma unroll
        for (int j = 0; j < 16; ++j) {
            int idx = (j << 8) + t;
            int o = idx >> 6, d = idx & 63;
            wpT[(((ki << 6) + o) << 6) + d] = f2bf_bits(tile[d * 65 + o]);
        }
    } else {                                      // ---- bias ----
        for (int idx = t; idx < 384; idx += 256) {
            int bt = idx >> 6, o = idx & 63;
            float bsum = 0.f;
            for (int d = 0; d < 64; ++d)
                bsum += time_emb[(bt << 6) + d] * bias_pool[(d << 6) + o];
            biasw[idx] = bsum;
        }
    }
}

// ---------------- k_attn: pipelined barrier-free flash attention -----------
// Block = 4 waves, 32 q rows; wave w owns keys [w*1024, w*1024+1024).
// Straight-line macro form: explicit named K/V register buffers, peeled
// epilogue pair, no structs/lambdas.
__global__ __launch_bounds__(256, 3) void k_attn(const unsigned short* __restrict__ e_bf,
                                                 const unsigned short* __restrict__ eq_bf,
                                                 const unsigned short* __restrict__ xT,
                                                 float* __restrict__ xg2) {
    __shared__ __align__(16) float Obuf[2][32 * 68];   // 17.4 KB merge buffers
    __shared__ float l_s[4][32];
    const int tid  = threadIdx.x;
    const int w    = tid >> 6;
    const int lane = tid & 63;
    const int l32  = lane & 31;
    const int h    = lane >> 5;

    // XCD-aware swizzle (bijective over 768)
    const int bid   = blockIdx.x;
    const int x8    = bid & 7;
    const int g     = (bid >> 3) & 31;
    const int r3    = bid >> 8;
    const int combo = x8 * 3 + r3;               // 0..23
    const int bt    = combo >> 2;
    const int qbase = ((((combo & 3) << 5) + g) << 5);

    const unsigned short* eb  = e_bf  + ((size_t)bt << 18);
    const unsigned short* eqb = eq_bf + ((size_t)bt << 18);
    const unsigned short* xb  = xT    + ((size_t)bt << 18);

    // Q as B-operand (pre-scaled by log2e): lane n=l32=q, k=h*8+j, d=c*16+k
    bf16x8 qf[4];
    #pragma unroll
    for (int c = 0; c < 4; ++c)
        qf[c] = *(const bf16x8*)(eqb + ((qbase + l32) << 6) + (c << 4) + (h << 3));

    f32x16 O0 = zero16(), O1 = zero16();
    float ls = 0.f;

    const int kstart = w << 10;
    const unsigned short* kr = eb + ((size_t)(kstart + l32) << 6) + (h << 3);
    const unsigned short* vr = xb + ((size_t)l32 << 12) + kstart + (h << 3);

    bf16x8 kA0, kA1, kA2, kA3, vA0, vA1, vA2, vA3;
    bf16x8 kB0, kB1, kB2, kB3, vB0, vB1, vB2, vB3;

#define LOAD_GRP(gi, K0, K1, K2, K3, V0, V1, V2, V3)                    \
    {                                                                   \
        const unsigned short* kp = kr + (gi) * 2048;                    \
        const unsigned short* vp = vr + ((gi) << 5);                    \
        K0 = *(const bf16x8*)(kp);                                      \
        K1 = *(const bf16x8*)(kp + 16);                                 \
        K2 = *(const bf16x8*)(kp + 32);                                 \
        K3 = *(const bf16x8*)(kp + 48);                                 \
        V0 = *(const bf16x8*)(vp);                                      \
        V1 = *(const bf16x8*)(vp + (32 << 12));                         \
        V2 = *(const bf16x8*)(vp + 16);                                 \
        V3 = *(const bf16x8*)(vp + 16 + (32 << 12));                    \
    }

#define COMPUTE_GRP(K0, K1, K2, K3, V0, V1, V2, V3)                     \
    {                                                                   \
        f32x16 S = zero16();                                            \
        S = mfma32(K0, qf[0], S);                                       \
        S = mfma32(K1, qf[1], S);                                       \
        S = mfma32(K2, qf[2], S);                                       \
        S = mfma32(K3, qf[3], S);                                       \
        float p[16];                                                    \
        _Pragma("unroll")                                               \
        for (int r = 0; r < 16; ++r) { p[r] = exp2f(S[r]); ls += p[r]; }\
        float r0[4], r1[4];                                             \
        _Pragma("unroll")                                               \
        for (int j = 0; j < 4; ++j) {                                   \
            r0[j] = __shfl_xor(h ? p[j]     : p[4 + j],  32);           \
            r1[j] = __shfl_xor(h ? p[8 + j] : p[12 + j], 32);           \
        }                                                               \
        bf16x8 pf0, pf1;                                                \
        _Pragma("unroll")                                               \
        for (int j = 0; j < 4; ++j) {                                   \
            pf0[j]     = (__bf16)(h ? r0[j]     : p[j]);                \
            pf0[4 + j] = (__bf16)(h ? p[4 + j]  : r0[j]);               \
            pf1[j]     = (__bf16)(h ? r1[j]     : p[8 + j]);            \
            pf1[4 + j] = (__bf16)(h ? p[12 + j] : r1[j]);               \
        }                                                               \
        O0 = mfma32(pf0, V0, O0);                                       \
        O1 = mfma32(pf0, V1, O1);                                       \
        O0 = mfma32(pf1, V2, O0);                                       \
        O1 = mfma32(pf1, V3, O1);                                       \
    }

    LOAD_GRP(0, kA0, kA1, kA2, kA3, vA0, vA1, vA2, vA3);
    for (int gi = 0; gi < 30; gi += 2) {
        LOAD_GRP(gi + 1, kB0, kB1, kB2, kB3, vB0, vB1, vB2, vB3);
        COMPUTE_GRP(kA0, kA1, kA2, kA3, vA0, vA1, vA2, vA3);
        LOAD_GRP(gi + 2, kA0, kA1, kA2, kA3, vA0, vA1, vA2, vA3);
        COMPUTE_GRP(kB0, kB1, kB2, kB3, vB0, vB1, vB2, vB3);
    }
    LOAD_GRP(31, kB0, kB1, kB2, kB3, vB0, vB1, vB2, vB3);
    COMPUTE_GRP(kA0, kA1, kA2, kA3, vA0, vA1, vA2, vA3);
    COMPUTE_GRP(kB0, kB1, kB2, kB3, vB0, vB1, vB2, vB3);
#undef LOAD_GRP
#undef COMPUTE_GRP

    // ---- merge: l across h, then O across 4 waves via 2 LDS buffers ----
    float lsum2 = ls + __shfl_xor(ls, 32);
    if (h == 0) l_s[w][l32] = lsum2;
    float* buf = Obuf[w & 1];
    if (w < 2) {
        #pragma unroll
        for (int r = 0; r < 16; ++r) {
            int qrow = (r & 3) + ((r >> 2) << 3) + (h << 2);
            buf[qrow * 68 + l32]      = O0[r];
            buf[qrow * 68 + 32 + l32] = O1[r];
        }
    }
    __syncthreads();
    if (w >= 2) {
        #pragma unroll
        for (int r = 0; r < 16; ++r) {
            int qrow = (r & 3) + ((r >> 2) << 3) + (h << 2);
            buf[qrow * 68 + l32]      += O0[r];
            buf[qrow * 68 + 32 + l32] += O1[r];
        }
    }
    __syncthreads();
    {
        int q  = tid >> 3;
        int d0 = (tid & 7) << 3;
        float inv = 1.f / (l_s[0][q] + l_s[1][q] + l_s[2][q] + l_s[3][q]);
        const float* b0 = Obuf[0] + q * 68 + d0;
        const float* b1 = Obuf[1] + q * 68 + d0;
        float* dst = xg2 + (((size_t)(bt << 12) + qbase + q) << 6) + d0;
        #pragma unroll
        for (int i = 0; i < 8; ++i) dst[i] = (b0[i] + b1[i]) * inv;
    }
}

// ---------------- k_hyper: fused hypernetwork contraction (round-4) --------
__global__ __launch_bounds__(256, 2) void k_hyper(const float* __restrict__ x,
                                                  const float* __restrict__ xg2,
                                                  const unsigned short* __restrict__ ne_bf,
                                                  const unsigned short* __restrict__ wpT,
                                                  const float* __restrict__ bias_ws,
                                                  float* __restrict__ out) {
    __shared__ float smem[13056];          // 52.2 KB: xg (4x3104) then red (4x3264)
    const int t    = threadIdx.x;
    const int w    = t >> 6;
    const int lane = t & 63;
    const int l16  = lane & 15;
    const int quad = lane >> 4;
    const int n0   = (blockIdx.x >> 1) << 4;
    const int oh   = blockIdx.x & 1;       // o-half

    float* xg_s = smem + w * 3104;
    const float* src = (w < 2) ? x : xg2;
    const int i0 = (w & 1) << 5;
    for (int it = 0; it < 48; ++it) {
        int j  = (it << 6) + lane;         // 0..3071
        int kk = j & 31;
        int btnl = j >> 5;                 // 0..95
        int bt = btnl % 6;
        int nl = btnl / 6;
        xg_s[kk * 97 + btnl] =
            src[(((size_t)(bt << 12) + n0 + nl) << 6) + i0 + kk];
    }
    __syncthreads();

    const unsigned short* nb = ne_bf + ((n0 + l16) << 6) + (quad << 3);
    bf16x8 a0 = *(const bf16x8*)(nb);
    bf16x8 a1 = *(const bf16x8*)(nb + 32);

    float oac[2][4][6];
    #pragma unroll
    for (int oc = 0; oc < 2; ++oc)
        #pragma unroll
        for (int r = 0; r < 4; ++r)
            #pragma unroll
            for (int bt = 0; bt < 6; ++bt) oac[oc][r][bt] = 0.f;

    const int ki_base = w << 5;
    #pragma unroll 2
    for (int kk = 0; kk < 32; ++kk) {
        const int ki = ki_base + kk;
        float g[4][6];
        #pragma unroll
        for (int r = 0; r < 4; ++r) {
            const float* gp = xg_s + kk * 97 + ((quad << 2) + r) * 6;
            #pragma unroll
            for (int bt = 0; bt < 6; ++bt) g[r][bt] = gp[bt];
        }
        #pragma unroll
        for (int oc = 0; oc < 2; ++oc) {
            const unsigned short* bp =
                wpT + (((ki << 6) + ((oh * 2 + oc) << 4) + l16) << 6) + (quad << 3);
            bf16x8 b0 = *(const bf16x8*)(bp);
            bf16x8 b1 = *(const bf16x8*)(bp + 32);
            f32x4 wf = mfma16(a0, b0, f32x4{0.f, 0.f, 0.f, 0.f});
            wf = mfma16(a1, b1, wf);
            #pragma unroll
            for (int r = 0; r < 4; ++r)
                #pragma unroll
                for (int bt = 0; bt < 6; ++bt)
                    oac[oc][r][bt] += wf[r] * g[r][bt];
        }
    }

    __syncthreads();                        // xg_s dead; smem becomes red
    #pragma unroll
    for (int oc = 0; oc < 2; ++oc)
        #pragma unroll
        for (int r = 0; r < 4; ++r)
            #pragma unroll
            for (int bt = 0; bt < 6; ++bt)
                smem[w * 3264 + ((quad << 2) + r) * 204 + bt * 34 + (oc << 4) + l16]
                    = oac[oc][r][bt];
    __syncthreads();
    #pragma unroll
    for (int rr = 0; rr < 4; ++rr) {
        int nl = (w << 2) + rr;
        #pragma unroll
        for (int bp2 = 0; bp2 < 3; ++bp2) {
            int bt = bp2 * 2 + (lane >> 5);
            int ol = lane & 31;
            int o  = (oh << 5) + ol;
            int a  = nl * 204 + bt * 34 + ol;
            float v = smem[a] + smem[a + 3264] + smem[a + 6528] + smem[a + 9792]
                    + bias_ws[(bt << 6) + o];
            out[(((size_t)(bt << 12) + n0 + nl) << 6) + o] = v;
        }
    }
}

// ---------------------------------------------------------------------------
extern "C" void kernel_launch(void* const* d_in, const int* in_sizes, int n_in,
                              void* d_out, int out_size, void* d_ws, size_t ws_size,
                              hipStream_t stream) {
    const float* x         = (const float*)d_in[0];
    const float* node_emb  = (const float*)d_in[1];
    const float* time_emb  = (const float*)d_in[2];
    const float* wp        = (const float*)d_in[3];
    const float* bias_pool = (const float*)d_in[4];
    const float* gamma     = (const float*)d_in[5];
    const float* beta      = (const float*)d_in[6];
    float* out = (float*)d_out;

    char* wsb = (char*)d_ws;
    unsigned short* e_bf  = (unsigned short*)(wsb);                  // 3 MB
    unsigned short* eq_bf = (unsigned short*)(wsb + 3145728);        // 3 MB
    unsigned short* xT    = (unsigned short*)(wsb + 6291456);        // 3 MB
    float*          xg2   = (float*)         (wsb + 9437184);        // 6.3 MB
    unsigned short* wpT   = (unsigned short*)(wsb + 15728640);       // 1 MB
    unsigned short* ne_bf = (unsigned short*)(wsb + 16777216);       // 0.5 MB
    float*          biasw = (float*)         (wsb + 17301504);       // 1.5 KB

    k_prep<<<7681, 256, 0, stream>>>(x, node_emb, time_emb, wp, bias_pool,
                                     gamma, beta, e_bf, eq_bf, xT, ne_bf, wpT, biasw);
    k_attn<<<768, 256, 0, stream>>>(e_bf, eq_bf, xT, xg2);
    k_hyper<<<512, 256, 0, stream>>>(x, xg2, ne_bf, wpT, biasw, out);
}